// Round 7
// baseline (392.035 us; speedup 1.0000x reference)
//
#include <hip/hip_runtime.h>
#include <hip/hip_bf16.h>

// Linear4bit NF4: y[2048,11008] = x[2048,4096] @ dequant(W)[11008,4096]^T + bias
// R7 = R6 with the compile fix: __builtin_nontemporal_store needs a clang
//   ext_vector type, not HIP's ushort4 class -> u16x4 typedef.
//   Theory under test (unchanged): prep streams 107MB of writes through
//   4MB/XCD L2 with cached stores -> allocation thrash. GEMM provably doesn't
//   use wb L2 residency (FETCH ~316MB, time-insensitive), so NT stores are
//   free on the consumer side.
//   gemm: unchanged from R5 (m97 structure + XOR-swizzled LDS + bijective XCD
//   chunk swizzle; FETCH 400->316MB confirmed, time-neutral -> kept).

#define IN_F   4096
#define OUT_F  11008
#define M_ROWS 2048
#define BM 128
#define BN 128
#define BK 64
#define LDSS 72   // fused-fallback padded stride

#define M_TILES (M_ROWS / BM)            // 16
#define N_TILES (OUT_F / BN)             // 86
#define NWG     (M_TILES * N_TILES)      // 1376 = 8 * 172
#define CPX     (NWG / 8)                // 172 blocks per XCD chunk

typedef short  s16x8 __attribute__((ext_vector_type(8)));
typedef unsigned short u16x8 __attribute__((ext_vector_type(8)));
typedef unsigned short u16x4 __attribute__((ext_vector_type(4)));
typedef float  f32x4 __attribute__((ext_vector_type(4)));
typedef int    i32x4 __attribute__((ext_vector_type(4)));
typedef unsigned int u32x4 __attribute__((ext_vector_type(4)));

__device__ const float NF4_C[16] = {
    -1.0f, -0.6961928009986877f, -0.5250730514526367f, -0.39491748809814453f,
    -0.28444138169288635f, -0.18477343022823334f, -0.09105003625154495f, 0.0f,
    0.07958029955625534f, 0.16093020141124725f, 0.24611230194568634f,
    0.33791524171829224f, 0.44070982933044434f, 0.5626170039176941f,
    0.7229568362236023f, 1.0f};

static __device__ __forceinline__ unsigned short f2bf(float f) {
    union { float f; unsigned int u; } c;
    c.f = f;
    unsigned int u = c.u;
    u += 0x7fffu + ((u >> 16) & 1u);
    return (unsigned short)(u >> 16);
}

static __device__ __forceinline__ void gload_lds16(const void* g, void* l) {
    __builtin_amdgcn_global_load_lds(
        (const __attribute__((address_space(1))) void*)g,
        (__attribute__((address_space(3))) void*)l, 16, 0, 0);
}

// ---------------- phase 1: dequant W + convert x (NT loads AND stores) --------
#define DQ_BLOCKS 11008
#define CV_BLOCKS 4096

__global__ __launch_bounds__(256)
void prep_kernel(const float* __restrict__ x,
                 const int* __restrict__ packed,
                 const float* __restrict__ absmax,
                 unsigned short* __restrict__ xb,
                 unsigned short* __restrict__ wb) {
    if (blockIdx.x < DQ_BLOCKS) {
        __shared__ float tab_hi[256];
        __shared__ float tab_lo[256];
        tab_hi[threadIdx.x] = NF4_C[threadIdx.x >> 4];
        tab_lo[threadIdx.x] = NF4_C[threadIdx.x & 15];
        __syncthreads();

        const size_t u0 = (size_t)blockIdx.x * 512 + threadIdx.x;
#pragma unroll
        for (int h = 0; h < 2; ++h) {
            const size_t u = u0 + h * 256;
            i32x4 v = __builtin_nontemporal_load(
                reinterpret_cast<const i32x4*>(packed) + u);
            const float s = absmax[u >> 3];   // 8 weights/unit, 64-aligned blocks
            unsigned int ow[4];
#pragma unroll
            for (int j = 0; j < 4; ++j) {
                const int b = v[j] & 0xFF;
                ow[j] = (unsigned int)f2bf(tab_hi[b] * s)
                      | ((unsigned int)f2bf(tab_lo[b] * s) << 16);
            }
            __builtin_nontemporal_store((u32x4){ow[0], ow[1], ow[2], ow[3]},
                                        reinterpret_cast<u32x4*>(wb) + u);
        }
    } else {
        const size_t u0 = (size_t)(blockIdx.x - DQ_BLOCKS) * 512 + threadIdx.x;
#pragma unroll
        for (int h = 0; h < 2; ++h) {
            const size_t u = u0 + h * 256;
            f32x4 v = __builtin_nontemporal_load(
                reinterpret_cast<const f32x4*>(x) + u);
            u16x4 o;
            o[0] = f2bf(v[0]); o[1] = f2bf(v[1]); o[2] = f2bf(v[2]); o[3] = f2bf(v[3]);
            __builtin_nontemporal_store(o, reinterpret_cast<u16x4*>(xb) + u);
        }
    }
}

// ---------------- phase 2: bf16 GEMM, m97 structure + XOR swizzle -------------
__global__ __launch_bounds__(256, 2)
void gemm_bt_kernel(const unsigned short* __restrict__ xb,   // [2048,4096] bf16
                    const unsigned short* __restrict__ wb,   // [11008,4096] bf16
                    const float* __restrict__ bias,
                    float* __restrict__ out) {
    __shared__ __align__(16) unsigned short As[BM * BK];
    __shared__ __align__(16) unsigned short Bs[BN * BK];

    const int tid  = threadIdx.x;
    const int lane = tid & 63;
    const int wave = tid >> 6;
    const int quad = lane >> 4;
    const int l16  = lane & 15;
    const int wm = wave & 1;
    const int wn = wave >> 1;

    // T1 XCD swizzle (bijective, NWG % 8 == 0): chunk of CPX consecutive
    // work-ids per XCD; m fast inside a chunk so the 16 blocks sharing one wb
    // N-panel run temporally adjacent on the same XCD's L2.
    const int orig = blockIdx.x;
    const int wg   = (orig & 7) * CPX + (orig >> 3);
    const int mBase = (wg & (M_TILES - 1)) * BM;    // m fast
    const int nBase = (wg >> 4) * BN;

    // staging: LDS[row][c] holds global 16B-chunk (c ^ (row&7)) of that row.
    const int srow = tid >> 3;           // 0..31 (+32*i)
    const int sc   = tid & 7;            // LDS chunk (dest stays lane-contiguous)
    const int scS  = sc ^ (srow & 7);    // swizzled global source chunk

    f32x4 acc[4][4];
#pragma unroll
    for (int mi = 0; mi < 4; ++mi)
#pragma unroll
        for (int ni = 0; ni < 4; ++ni)
            acc[mi][ni] = (f32x4){0.f, 0.f, 0.f, 0.f};

    const unsigned short* aSrc = xb + (size_t)(mBase + srow) * IN_F + scS * 8;
    const unsigned short* bSrc = wb + (size_t)(nBase + srow) * IN_F + scS * 8;

    const int sw = l16 & 7;   // reader un-swizzle key (row&7 == l16&7)

    for (int kt = 0; kt < IN_F / BK; ++kt) {
        const int k0 = kt * BK;
        __syncthreads();
#pragma unroll
        for (int i = 0; i < 4; ++i)
            gload_lds16(aSrc + (size_t)i * 32 * IN_F + k0, &As[(i * 32 + srow) * BK + sc * 8]);
#pragma unroll
        for (int i = 0; i < 4; ++i)
            gload_lds16(bSrc + (size_t)i * 32 * IN_F + k0, &Bs[(i * 32 + srow) * BK + sc * 8]);
        __syncthreads();

#pragma unroll
        for (int kk = 0; kk < 2; ++kk) {
            const int q  = kk * 4 + quad;        // wanted global chunk
            const int rd = (q ^ sw) * 8;         // un-swizzled LDS offset (elems)
            s16x8 af[4], bfr[4];
#pragma unroll
            for (int mi = 0; mi < 4; ++mi)
                af[mi] = *reinterpret_cast<const s16x8*>(
                    &As[(wm * 64 + mi * 16 + l16) * BK + rd]);
#pragma unroll
            for (int ni = 0; ni < 4; ++ni)
                bfr[ni] = *reinterpret_cast<const s16x8*>(
                    &Bs[(wn * 64 + ni * 16 + l16) * BK + rd]);
#pragma unroll
            for (int mi = 0; mi < 4; ++mi)
#pragma unroll
                for (int ni = 0; ni < 4; ++ni)
                    acc[mi][ni] = __builtin_amdgcn_mfma_f32_16x16x32_bf16(
                        af[mi], bfr[ni], acc[mi][ni], 0, 0, 0);
        }
    }

    float bv[4];
#pragma unroll
    for (int ni = 0; ni < 4; ++ni)
        bv[ni] = bias[nBase + wn * 64 + ni * 16 + l16];
#pragma unroll
    for (int mi = 0; mi < 4; ++mi) {
        const int rbase = mBase + wm * 64 + mi * 16 + quad * 4;
#pragma unroll
        for (int ni = 0; ni < 4; ++ni) {
            const int col = nBase + wn * 64 + ni * 16 + l16;
#pragma unroll
            for (int r = 0; r < 4; ++r)
                __builtin_nontemporal_store(acc[mi][ni][r] + bv[ni],
                    &out[(size_t)(rbase + r) * OUT_F + col]);
        }
    }
}

// ---------------- fallback: fused kernel (small ws) ----------------
__global__ __launch_bounds__(256, 2)
void nf4_linear_fused(const float* __restrict__ x,
                      const int* __restrict__ packed,
                      const float* __restrict__ absmax,
                      const float* __restrict__ bias,
                      float* __restrict__ out) {
    __shared__ __align__(16) unsigned short As[BM * LDSS];
    __shared__ __align__(16) unsigned short Bs[BN * LDSS];
    __shared__ float2 tab[256];

    const int tid  = threadIdx.x;
    const int lane = tid & 63;
    const int wave = tid >> 6;
    const int quad = lane >> 4;
    const int l16  = lane & 15;
    const int wm = wave & 1;
    const int wn = wave >> 1;
    const int mBase = blockIdx.y * BM;
    const int nBase = blockIdx.x * BN;

    tab[tid] = make_float2(NF4_C[tid >> 4], NF4_C[tid & 15]);

    f32x4 acc[4][4];
#pragma unroll
    for (int mi = 0; mi < 4; ++mi)
#pragma unroll
        for (int ni = 0; ni < 4; ++ni)
            acc[mi][ni] = (f32x4){0.f, 0.f, 0.f, 0.f};

    const int brow  = tid >> 1;
    const int bhalf = tid & 1;
    const int ng    = nBase + brow;

    for (int kt = 0; kt < IN_F / BK; ++kt) {
        const int k0 = kt * BK;
        __syncthreads();
#pragma unroll
        for (int i = 0; i < 4; ++i) {
            int gid = tid + i * 256;
            int row = gid >> 3;
            int c8  = gid & 7;
            const float4* src = reinterpret_cast<const float4*>(
                x + (size_t)(mBase + row) * IN_F + k0 + c8 * 8);
            float4 v0 = src[0];
            float4 v1 = src[1];
            u16x8 o;
            o[0] = f2bf(v0.x); o[1] = f2bf(v0.y); o[2] = f2bf(v0.z); o[3] = f2bf(v0.w);
            o[4] = f2bf(v1.x); o[5] = f2bf(v1.y); o[6] = f2bf(v1.z); o[7] = f2bf(v1.w);
            *reinterpret_cast<u16x8*>(&As[row * LDSS + c8 * 8]) = o;
        }
        {
            const float scale = absmax[(size_t)ng * 64 + (k0 >> 6)];
            const int4* bp = reinterpret_cast<const int4*>(
                packed + (size_t)ng * (IN_F / 2) + (k0 >> 1) + bhalf * 16);
            const int colw = bhalf * 32;
#pragma unroll
            for (int c = 0; c < 4; ++c) {
                int4 v = bp[c];
                int vs[4] = {v.x, v.y, v.z, v.w};
                unsigned int ow[4];
#pragma unroll
                for (int j = 0; j < 4; ++j) {
                    float2 t = tab[vs[j] & 0xFF];
                    ow[j] = (unsigned int)f2bf(t.x * scale)
                          | ((unsigned int)f2bf(t.y * scale) << 16);
                }
                *reinterpret_cast<uint4*>(&Bs[brow * LDSS + colw + c * 8]) =
                    *reinterpret_cast<const uint4*>(ow);
            }
        }
        __syncthreads();

#pragma unroll
        for (int kk = 0; kk < 2; ++kk) {
            const int kof = kk * 32 + quad * 8;
            s16x8 af[4], bfr[4];
#pragma unroll
            for (int mi = 0; mi < 4; ++mi)
                af[mi] = *reinterpret_cast<const s16x8*>(
                    &As[(wm * 64 + mi * 16 + l16) * LDSS + kof]);
#pragma unroll
            for (int ni = 0; ni < 4; ++ni)
                bfr[ni] = *reinterpret_cast<const s16x8*>(
                    &Bs[(wn * 64 + ni * 16 + l16) * LDSS + kof]);
#pragma unroll
            for (int mi = 0; mi < 4; ++mi)
#pragma unroll
                for (int ni = 0; ni < 4; ++ni)
                    acc[mi][ni] = __builtin_amdgcn_mfma_f32_16x16x32_bf16(
                        af[mi], bfr[ni], acc[mi][ni], 0, 0, 0);
        }
    }

    float bv[4];
#pragma unroll
    for (int ni = 0; ni < 4; ++ni)
        bv[ni] = bias[nBase + wn * 64 + ni * 16 + l16];
#pragma unroll
    for (int mi = 0; mi < 4; ++mi) {
        const int rbase = mBase + wm * 64 + mi * 16 + quad * 4;
#pragma unroll
        for (int ni = 0; ni < 4; ++ni) {
            const int col = nBase + wn * 64 + ni * 16 + l16;
#pragma unroll
            for (int r = 0; r < 4; ++r)
                out[(size_t)(rbase + r) * OUT_F + col] = acc[mi][ni][r] + bv[ni];
        }
    }
}

extern "C" void kernel_launch(void* const* d_in, const int* in_sizes, int n_in,
                              void* d_out, int out_size, void* d_ws, size_t ws_size,
                              hipStream_t stream) {
    const float* x      = (const float*)d_in[0];
    const int*   packed = (const int*)d_in[1];
    const float* absmax = (const float*)d_in[2];
    const float* bias   = (const float*)d_in[3];
    float* out = (float*)d_out;

    const size_t xb_bytes = (size_t)M_ROWS * IN_F * 2;          // 16,777,216
    const size_t wb_bytes = (size_t)OUT_F * IN_F * 2;           // 90,177,536
    if (ws_size >= xb_bytes + wb_bytes) {
        unsigned short* xb = (unsigned short*)d_ws;
        unsigned short* wb = (unsigned short*)((char*)d_ws + xb_bytes);
        prep_kernel<<<dim3(DQ_BLOCKS + CV_BLOCKS), dim3(256), 0, stream>>>(
            x, packed, absmax, xb, wb);
        gemm_bt_kernel<<<dim3(NWG), dim3(256), 0, stream>>>(
            xb, wb, bias, out);
    } else {
        nf4_linear_fused<<<dim3(OUT_F / BN, M_ROWS / BM), dim3(256), 0, stream>>>(
            x, packed, absmax, bias, out);
    }
}

// Round 8
// 362.943 us; speedup vs baseline: 1.0802x; 1.0802x over previous
//
#include <hip/hip_runtime.h>
#include <hip/hip_bf16.h>

// Linear4bit NF4: y[2048,11008] = x[2048,4096] @ dequant(W)[11008,4096]^T + bias
// R8 = R5 exact (best verified: 354.6us) + __launch_bounds__(256,4) on the GEMM.
//   R7 post-mortem: NT stores in prep evicted wb/xb from L2 early -> gemm panel
//   re-reads missed; gemm 191->225us. Reverted.
//   Occupancy theory: resources allow ~4 blocks/CU (LDS 32KB->5, VGPR 56 +
//   ~64 AGPR = 120 -> 4 waves/SIMD) but measured occupancy ~31% (~2.5
//   blocks/CU) under launch_bounds(256,2). The m97 structure's ~20% stall is
//   the per-tile vmcnt(0) drain; co-resident blocks hide it (m114). Raise the
//   declared min to 4 waves/EU. 120 regs <= 512/4=128 -> no spill expected.
// Phase 1 (R0/R5 exact): x fp32->bf16, NF4 dequant W->bf16 into d_ws (NT loads,
//   cached stores).
// Phase 2: m97-style bf16 GEMM + XOR-swizzled LDS + bijective XCD chunk swizzle
//   (FETCH 400->316MB verified).

#define IN_F   4096
#define OUT_F  11008
#define M_ROWS 2048
#define BM 128
#define BN 128
#define BK 64
#define LDSS 72   // fused-fallback padded stride

#define M_TILES (M_ROWS / BM)            // 16
#define N_TILES (OUT_F / BN)             // 86
#define NWG     (M_TILES * N_TILES)      // 1376 = 8 * 172
#define CPX     (NWG / 8)                // 172 blocks per XCD chunk

typedef short  s16x8 __attribute__((ext_vector_type(8)));
typedef unsigned short u16x8 __attribute__((ext_vector_type(8)));
typedef float  f32x4 __attribute__((ext_vector_type(4)));
typedef int    i32x4 __attribute__((ext_vector_type(4)));
typedef unsigned int u32x4 __attribute__((ext_vector_type(4)));

__device__ const float NF4_C[16] = {
    -1.0f, -0.6961928009986877f, -0.5250730514526367f, -0.39491748809814453f,
    -0.28444138169288635f, -0.18477343022823334f, -0.09105003625154495f, 0.0f,
    0.07958029955625534f, 0.16093020141124725f, 0.24611230194568634f,
    0.33791524171829224f, 0.44070982933044434f, 0.5626170039176941f,
    0.7229568362236023f, 1.0f};

static __device__ __forceinline__ unsigned short f2bf(float f) {
    union { float f; unsigned int u; } c;
    c.f = f;
    unsigned int u = c.u;
    u += 0x7fffu + ((u >> 16) & 1u);
    return (unsigned short)(u >> 16);
}

static __device__ __forceinline__ void gload_lds16(const void* g, void* l) {
    __builtin_amdgcn_global_load_lds(
        (const __attribute__((address_space(1))) void*)g,
        (__attribute__((address_space(3))) void*)l, 16, 0, 0);
}

// ---------------- phase 1 (R0/R5 exact): dequant W + convert x ----------------
#define DQ_BLOCKS 11008
#define CV_BLOCKS 4096

__global__ __launch_bounds__(256)
void prep_kernel(const float* __restrict__ x,
                 const int* __restrict__ packed,
                 const float* __restrict__ absmax,
                 unsigned short* __restrict__ xb,
                 unsigned short* __restrict__ wb) {
    if (blockIdx.x < DQ_BLOCKS) {
        __shared__ float tab_hi[256];
        __shared__ float tab_lo[256];
        tab_hi[threadIdx.x] = NF4_C[threadIdx.x >> 4];
        tab_lo[threadIdx.x] = NF4_C[threadIdx.x & 15];
        __syncthreads();

        const size_t u0 = (size_t)blockIdx.x * 512 + threadIdx.x;
#pragma unroll
        for (int h = 0; h < 2; ++h) {
            const size_t u = u0 + h * 256;
            i32x4 v = __builtin_nontemporal_load(
                reinterpret_cast<const i32x4*>(packed) + u);
            const float s = absmax[u >> 3];   // 8 weights/unit, 64-aligned blocks
            unsigned int ow[4];
#pragma unroll
            for (int j = 0; j < 4; ++j) {
                const int b = v[j] & 0xFF;
                ow[j] = (unsigned int)f2bf(tab_hi[b] * s)
                      | ((unsigned int)f2bf(tab_lo[b] * s) << 16);
            }
            *(reinterpret_cast<u32x4*>(wb) + u) = (u32x4){ow[0], ow[1], ow[2], ow[3]};
        }
    } else {
        const size_t u0 = (size_t)(blockIdx.x - DQ_BLOCKS) * 512 + threadIdx.x;
#pragma unroll
        for (int h = 0; h < 2; ++h) {
            const size_t u = u0 + h * 256;
            f32x4 v = __builtin_nontemporal_load(
                reinterpret_cast<const f32x4*>(x) + u);
            ushort4 o;
            o.x = f2bf(v[0]); o.y = f2bf(v[1]); o.z = f2bf(v[2]); o.w = f2bf(v[3]);
            *(reinterpret_cast<ushort4*>(xb) + u) = o;
        }
    }
}

// ---------------- phase 2: bf16 GEMM, m97 structure + XOR swizzle -------------
__global__ __launch_bounds__(256, 4)
void gemm_bt_kernel(const unsigned short* __restrict__ xb,   // [2048,4096] bf16
                    const unsigned short* __restrict__ wb,   // [11008,4096] bf16
                    const float* __restrict__ bias,
                    float* __restrict__ out) {
    __shared__ __align__(16) unsigned short As[BM * BK];
    __shared__ __align__(16) unsigned short Bs[BN * BK];

    const int tid  = threadIdx.x;
    const int lane = tid & 63;
    const int wave = tid >> 6;
    const int quad = lane >> 4;
    const int l16  = lane & 15;
    const int wm = wave & 1;
    const int wn = wave >> 1;

    // T1 XCD swizzle (bijective, NWG % 8 == 0): chunk of CPX consecutive
    // work-ids per XCD; m fast inside a chunk so the 16 blocks sharing one wb
    // N-panel run temporally adjacent on the same XCD's L2.
    const int orig = blockIdx.x;
    const int wg   = (orig & 7) * CPX + (orig >> 3);
    const int mBase = (wg & (M_TILES - 1)) * BM;    // m fast
    const int nBase = (wg >> 4) * BN;

    // staging: LDS[row][c] holds global 16B-chunk (c ^ (row&7)) of that row.
    const int srow = tid >> 3;           // 0..31 (+32*i)
    const int sc   = tid & 7;            // LDS chunk (dest stays lane-contiguous)
    const int scS  = sc ^ (srow & 7);    // swizzled global source chunk

    f32x4 acc[4][4];
#pragma unroll
    for (int mi = 0; mi < 4; ++mi)
#pragma unroll
        for (int ni = 0; ni < 4; ++ni)
            acc[mi][ni] = (f32x4){0.f, 0.f, 0.f, 0.f};

    const unsigned short* aSrc = xb + (size_t)(mBase + srow) * IN_F + scS * 8;
    const unsigned short* bSrc = wb + (size_t)(nBase + srow) * IN_F + scS * 8;

    const int sw = l16 & 7;   // reader un-swizzle key (row&7 == l16&7)

    for (int kt = 0; kt < IN_F / BK; ++kt) {
        const int k0 = kt * BK;
        __syncthreads();
#pragma unroll
        for (int i = 0; i < 4; ++i)
            gload_lds16(aSrc + (size_t)i * 32 * IN_F + k0, &As[(i * 32 + srow) * BK + sc * 8]);
#pragma unroll
        for (int i = 0; i < 4; ++i)
            gload_lds16(bSrc + (size_t)i * 32 * IN_F + k0, &Bs[(i * 32 + srow) * BK + sc * 8]);
        __syncthreads();

#pragma unroll
        for (int kk = 0; kk < 2; ++kk) {
            const int q  = kk * 4 + quad;        // wanted global chunk
            const int rd = (q ^ sw) * 8;         // un-swizzled LDS offset (elems)
            s16x8 af[4], bfr[4];
#pragma unroll
            for (int mi = 0; mi < 4; ++mi)
                af[mi] = *reinterpret_cast<const s16x8*>(
                    &As[(wm * 64 + mi * 16 + l16) * BK + rd]);
#pragma unroll
            for (int ni = 0; ni < 4; ++ni)
                bfr[ni] = *reinterpret_cast<const s16x8*>(
                    &Bs[(wn * 64 + ni * 16 + l16) * BK + rd]);
#pragma unroll
            for (int mi = 0; mi < 4; ++mi)
#pragma unroll
                for (int ni = 0; ni < 4; ++ni)
                    acc[mi][ni] = __builtin_amdgcn_mfma_f32_16x16x32_bf16(
                        af[mi], bfr[ni], acc[mi][ni], 0, 0, 0);
        }
    }

    float bv[4];
#pragma unroll
    for (int ni = 0; ni < 4; ++ni)
        bv[ni] = bias[nBase + wn * 64 + ni * 16 + l16];
#pragma unroll
    for (int mi = 0; mi < 4; ++mi) {
        const int rbase = mBase + wm * 64 + mi * 16 + quad * 4;
#pragma unroll
        for (int ni = 0; ni < 4; ++ni) {
            const int col = nBase + wn * 64 + ni * 16 + l16;
#pragma unroll
            for (int r = 0; r < 4; ++r)
                __builtin_nontemporal_store(acc[mi][ni][r] + bv[ni],
                    &out[(size_t)(rbase + r) * OUT_F + col]);
        }
    }
}

// ---------------- fallback: fused kernel (small ws) ----------------
__global__ __launch_bounds__(256, 2)
void nf4_linear_fused(const float* __restrict__ x,
                      const int* __restrict__ packed,
                      const float* __restrict__ absmax,
                      const float* __restrict__ bias,
                      float* __restrict__ out) {
    __shared__ __align__(16) unsigned short As[BM * LDSS];
    __shared__ __align__(16) unsigned short Bs[BN * LDSS];
    __shared__ float2 tab[256];

    const int tid  = threadIdx.x;
    const int lane = tid & 63;
    const int wave = tid >> 6;
    const int quad = lane >> 4;
    const int l16  = lane & 15;
    const int wm = wave & 1;
    const int wn = wave >> 1;
    const int mBase = blockIdx.y * BM;
    const int nBase = blockIdx.x * BN;

    tab[tid] = make_float2(NF4_C[tid >> 4], NF4_C[tid & 15]);

    f32x4 acc[4][4];
#pragma unroll
    for (int mi = 0; mi < 4; ++mi)
#pragma unroll
        for (int ni = 0; ni < 4; ++ni)
            acc[mi][ni] = (f32x4){0.f, 0.f, 0.f, 0.f};

    const int brow  = tid >> 1;
    const int bhalf = tid & 1;
    const int ng    = nBase + brow;

    for (int kt = 0; kt < IN_F / BK; ++kt) {
        const int k0 = kt * BK;
        __syncthreads();
#pragma unroll
        for (int i = 0; i < 4; ++i) {
            int gid = tid + i * 256;
            int row = gid >> 3;
            int c8  = gid & 7;
            const float4* src = reinterpret_cast<const float4*>(
                x + (size_t)(mBase + row) * IN_F + k0 + c8 * 8);
            float4 v0 = src[0];
            float4 v1 = src[1];
            u16x8 o;
            o[0] = f2bf(v0.x); o[1] = f2bf(v0.y); o[2] = f2bf(v0.z); o[3] = f2bf(v0.w);
            o[4] = f2bf(v1.x); o[5] = f2bf(v1.y); o[6] = f2bf(v1.z); o[7] = f2bf(v1.w);
            *reinterpret_cast<u16x8*>(&As[row * LDSS + c8 * 8]) = o;
        }
        {
            const float scale = absmax[(size_t)ng * 64 + (k0 >> 6)];
            const int4* bp = reinterpret_cast<const int4*>(
                packed + (size_t)ng * (IN_F / 2) + (k0 >> 1) + bhalf * 16);
            const int colw = bhalf * 32;
#pragma unroll
            for (int c = 0; c < 4; ++c) {
                int4 v = bp[c];
                int vs[4] = {v.x, v.y, v.z, v.w};
                unsigned int ow[4];
#pragma unroll
                for (int j = 0; j < 4; ++j) {
                    float2 t = tab[vs[j] & 0xFF];
                    ow[j] = (unsigned int)f2bf(t.x * scale)
                          | ((unsigned int)f2bf(t.y * scale) << 16);
                }
                *reinterpret_cast<uint4*>(&Bs[brow * LDSS + colw + c * 8]) =
                    *reinterpret_cast<const uint4*>(ow);
            }
        }
        __syncthreads();

#pragma unroll
        for (int kk = 0; kk < 2; ++kk) {
            const int kof = kk * 32 + quad * 8;
            s16x8 af[4], bfr[4];
#pragma unroll
            for (int mi = 0; mi < 4; ++mi)
                af[mi] = *reinterpret_cast<const s16x8*>(
                    &As[(wm * 64 + mi * 16 + l16) * LDSS + kof]);
#pragma unroll
            for (int ni = 0; ni < 4; ++ni)
                bfr[ni] = *reinterpret_cast<const s16x8*>(
                    &Bs[(wn * 64 + ni * 16 + l16) * LDSS + kof]);
#pragma unroll
            for (int mi = 0; mi < 4; ++mi)
#pragma unroll
                for (int ni = 0; ni < 4; ++ni)
                    acc[mi][ni] = __builtin_amdgcn_mfma_f32_16x16x32_bf16(
                        af[mi], bfr[ni], acc[mi][ni], 0, 0, 0);
        }
    }

    float bv[4];
#pragma unroll
    for (int ni = 0; ni < 4; ++ni)
        bv[ni] = bias[nBase + wn * 64 + ni * 16 + l16];
#pragma unroll
    for (int mi = 0; mi < 4; ++mi) {
        const int rbase = mBase + wm * 64 + mi * 16 + quad * 4;
#pragma unroll
        for (int ni = 0; ni < 4; ++ni) {
            const int col = nBase + wn * 64 + ni * 16 + l16;
#pragma unroll
            for (int r = 0; r < 4; ++r)
                out[(size_t)(rbase + r) * OUT_F + col] = acc[mi][ni][r] + bv[ni];
        }
    }
}

extern "C" void kernel_launch(void* const* d_in, const int* in_sizes, int n_in,
                              void* d_out, int out_size, void* d_ws, size_t ws_size,
                              hipStream_t stream) {
    const float* x      = (const float*)d_in[0];
    const int*   packed = (const int*)d_in[1];
    const float* absmax = (const float*)d_in[2];
    const float* bias   = (const float*)d_in[3];
    float* out = (float*)d_out;

    const size_t xb_bytes = (size_t)M_ROWS * IN_F * 2;          // 16,777,216
    const size_t wb_bytes = (size_t)OUT_F * IN_F * 2;           // 90,177,536
    if (ws_size >= xb_bytes + wb_bytes) {
        unsigned short* xb = (unsigned short*)d_ws;
        unsigned short* wb = (unsigned short*)((char*)d_ws + xb_bytes);
        prep_kernel<<<dim3(DQ_BLOCKS + CV_BLOCKS), dim3(256), 0, stream>>>(
            x, packed, absmax, xb, wb);
        gemm_bt_kernel<<<dim3(NWG), dim3(256), 0, stream>>>(
            xb, wb, bias, out);
    } else {
        nf4_linear_fused<<<dim3(OUT_F / BN, M_ROWS / BM), dim3(256), 0, stream>>>(
            x, packed, absmax, bias, out);
    }
}